// Round 2
// baseline (34362.454 us; speedup 1.0000x reference)
//
#include <hip/hip_runtime.h>
#include <float.h>
#include <math.h>

// Informer forward, MI355X. f32 everywhere (KV cross-cache optionally bf16).
// Adaptive batch-chunking so the workspace plan fits whatever ws_size gives us.
// B=64, STEPS=336, D_MODEL=512, H=8, DH=64, E_LAYERS=2, D_LAYERS=1, D_FF=512,
// FACTOR=5 -> U=30, LABEL_LEN=168, PRED_LEN=12.

#define UTOP 30
typedef unsigned int u32;
typedef unsigned short u16;

// ---------------- Threefry-2x32 (JAX partitionable path) ----------------
__device__ __forceinline__ u32 rotl32(u32 x, int d){ return (x<<d)|(x>>(32-d)); }

__device__ __forceinline__ void threefry(u32 k0, u32 k1, u32& x0, u32& x1){
  u32 k2 = k0 ^ k1 ^ 0x1BD11BDAu;
  x0 += k0; x1 += k1;
#define TFR(r) { x0 += x1; x1 = rotl32(x1,(r)); x1 ^= x0; }
  TFR(13) TFR(15) TFR(26) TFR(6)
  x0 += k1; x1 += k2 + 1u;
  TFR(17) TFR(29) TFR(16) TFR(24)
  x0 += k2; x1 += k0 + 2u;
  TFR(13) TFR(15) TFR(26) TFR(6)
  x0 += k0; x1 += k1 + 3u;
  TFR(17) TFR(29) TFR(16) TFR(24)
  x0 += k1; x1 += k2 + 4u;
  TFR(13) TFR(15) TFR(26) TFR(6)
  x0 += k2; x1 += k0 + 5u;
#undef TFR
}

__device__ __forceinline__ u16 f2bf(float f){
  u32 u = __float_as_uint(f);
  return (u16)((u + 0x7FFFu + ((u >> 16) & 1u)) >> 16);
}
__device__ __forceinline__ float bf2f(u16 h){ return __uint_as_float(((u32)h) << 16); }

// idx = jax.random.randint(fold_in(key(7), ctr), (L,30), 0, span), partitionable
__global__ void k_gen_idx(int* __restrict__ idx, int L, int span_i, u32 ctr){
  int n = L * UTOP;
  int j = blockIdx.x * blockDim.x + threadIdx.x;
  if (j >= n) return;
  u32 a0 = 0u, a1 = ctr; threefry(0u, 7u, a0, a1);       // fold_in -> new key
  u32 k1a = 0u, k1b = 0u; threefry(a0, a1, k1a, k1b);    // split[0] = enc(0,0)
  u32 k2a = 0u, k2b = 1u; threefry(a0, a1, k2a, k2b);    // split[1] = enc(0,1)
  u32 h0 = 0u, h1 = (u32)j; threefry(k1a, k1b, h0, h1);  // higher_bits = w0
  u32 l0 = 0u, l1 = (u32)j; threefry(k2a, k2b, l0, l1);  // lower_bits  = w0
  u32 span = (u32)span_i;
  u32 mult = 65536u % span; mult = (mult * mult) % span;
  u32 off  = (((h0 % span) * mult) + (l0 % span)) % span;
  idx[j] = (int)off;
}

// ---------------- Embedding: wrap-conv(3) + sinusoidal PE ----------------
// grid = rows*2 blocks x 256 (exact: rows*512 threads), x pre-offset by b0.
__global__ void k_embed(const float* __restrict__ x, const float* __restrict__ w,
                        float* __restrict__ out, int L, int xs){
  int i = blockIdx.x * blockDim.x + threadIdx.x;
  int d = i & 511; int r = i >> 9; int b = r / L; int l = r - b * L;
  int lm = (l == 0) ? L - 1 : l - 1;
  int lp = (l == L - 1) ? 0 : l + 1;
  const float* xb = x + b * xs;
  float tok = w[d*3] * xb[lm] + w[d*3+1] * xb[l] + w[d*3+2] * xb[lp];
  int jj = d >> 1;
  float div = expf((float)(2 * jj) * -0.017988946039015984f); // ln(10000)/512
  float arg = (float)l * div;
  float pe = (d & 1) ? cosf(arg) : sinf(arg);
  out[i] = tok + pe;
}

// ---- f32 GEMM: Out[rows,O] = X[rows,512] @ W[O,512]^T + bias, row-guarded ----
// grid (O/64, ceil(rows/64)), block 256. flags: bit0 = exact GELU, bit1 = bf16 out.
__global__ __launch_bounds__(256) void k_gemm512(
    const float* __restrict__ X, const float* __restrict__ W,
    const float* __restrict__ bias, void* __restrict__ Out,
    int O, int rows, int flags){
  __shared__ float As[16][72];
  __shared__ float Bs[16][72];
  int tid = threadIdx.x;
  int tc = tid & 15, tr = tid >> 4;
  int r0 = blockIdx.y << 6, c0 = blockIdx.x << 6;
  int rr = tid >> 2;            // 0..63
  int kc = (tid & 3) << 2;      // 0,4,8,12
  int xr = r0 + rr; if (xr >= rows) xr = rows - 1;   // clamp (stores guarded)
  float acc[4][4] = {{0.f,0.f,0.f,0.f},{0.f,0.f,0.f,0.f},
                     {0.f,0.f,0.f,0.f},{0.f,0.f,0.f,0.f}};
  for (int k0 = 0; k0 < 512; k0 += 16){
    float4 xa = *(const float4*)(X + (size_t)xr * 512 + k0 + kc);
    float4 xb = *(const float4*)(W + (size_t)(c0 + rr) * 512 + k0 + kc);
    As[kc+0][rr] = xa.x; As[kc+1][rr] = xa.y; As[kc+2][rr] = xa.z; As[kc+3][rr] = xa.w;
    Bs[kc+0][rr] = xb.x; Bs[kc+1][rr] = xb.y; Bs[kc+2][rr] = xb.z; Bs[kc+3][rr] = xb.w;
    __syncthreads();
#pragma unroll
    for (int kk = 0; kk < 16; kk++){
      float4 a4 = *(const float4*)(&As[kk][tr << 2]);
      float4 b4 = *(const float4*)(&Bs[kk][tc << 2]);
      float av[4] = {a4.x, a4.y, a4.z, a4.w};
      float bv[4] = {b4.x, b4.y, b4.z, b4.w};
#pragma unroll
      for (int i = 0; i < 4; i++)
#pragma unroll
        for (int j = 0; j < 4; j++)
          acc[i][j] = fmaf(av[i], bv[j], acc[i][j]);
    }
    __syncthreads();
  }
#pragma unroll
  for (int i = 0; i < 4; i++){
    int row = r0 + (tr << 2) + i;
    if (row >= rows) continue;
    float v[4];
#pragma unroll
    for (int j = 0; j < 4; j++){
      int c = c0 + (tc << 2) + j;
      float t = acc[i][j] + bias[c];
      if (flags & 1) t = 0.5f * t * (1.0f + erff(t * 0.7071067811865476f));
      v[j] = t;
    }
    size_t base = (size_t)row * O + c0 + (tc << 2);
    if (flags & 2){
      ushort4 u; u.x = f2bf(v[0]); u.y = f2bf(v[1]); u.z = f2bf(v[2]); u.w = f2bf(v[3]);
      *(ushort4*)((u16*)Out + base) = u;
    } else {
      float4 o; o.x = v[0]; o.y = v[1]; o.z = v[2]; o.w = v[3];
      *(float4*)((float*)Out + base) = o;
    }
  }
}

// ---------------- ProbAttention: M = max_u(QK_samp) - sum_u(QK_samp)/L ------
// one wave per (b,h,l) local to chunk; qkv rows (nbat*L, 1536)=[Q|K|V].
__global__ void k_prob_m(const float* __restrict__ qkv, const int* __restrict__ idx,
                         float* __restrict__ M, int L, int nwaves){
  int w = (blockIdx.x << 2) + (threadIdx.x >> 6);
  if (w >= nwaves) return;                  // wave-uniform exit
  int lane = threadIdx.x & 63;
  int l = w % L; int bh = w / L; int b = bh >> 3, h = bh & 7;
  float q = qkv[(size_t)(b * L + l) * 1536 + h * 64 + lane];
  float mx = -FLT_MAX, sm = 0.f;
  for (int u = 0; u < UTOP; u++){
    int ki = idx[l * UTOP + u];
    float kv = qkv[(size_t)(b * L + ki) * 1536 + 512 + h * 64 + lane];
    float p = q * kv;
#pragma unroll
    for (int o = 32; o; o >>= 1) p += __shfl_xor(p, o);
    mx = fmaxf(mx, p); sm += p;
  }
  if (lane == 0) M[w] = mx - sm / (float)L;
}

// stable top-30 (ties -> lower index), one wave per local (b,h)
__global__ void k_topk(const float* __restrict__ M, int* __restrict__ top, int L){
  __shared__ float s[336];
  int bh = blockIdx.x; int lane = threadIdx.x;
  for (int l = lane; l < L; l += 64) s[l] = M[bh * L + l];
  __syncthreads();
  for (int u = 0; u < UTOP; u++){
    float bv = -FLT_MAX; int bi = 0x7FFFFFFF;
    for (int l = lane; l < L; l += 64){
      float v = s[l];
      if (v > bv || (v == bv && l < bi)){ bv = v; bi = l; }
    }
#pragma unroll
    for (int o = 32; o; o >>= 1){
      float ov = __shfl_xor(bv, o); int oi = __shfl_xor(bi, o);
      if (ov > bv || (ov == bv && oi < bi)){ bv = ov; bi = oi; }
    }
    if (lane == 0){ top[bh * UTOP + u] = bi; s[bi] = -FLT_MAX; }
    __syncthreads();
  }
}

__global__ void k_meanv(const float* __restrict__ qkv, float* __restrict__ mv, int L){
  int bh = blockIdx.x; int e = threadIdx.x;
  int b = bh >> 3, h = bh & 7;
  float sm = 0.f;
  for (int l = 0; l < L; l++)
    sm += qkv[(size_t)(b * L + l) * 1536 + 1024 + h * 64 + e];
  mv[bh * 64 + e] = sm / (float)L;
}

__global__ void k_ctx_init(float* __restrict__ ctx, const float* __restrict__ mv, int L){
  int i = blockIdx.x * blockDim.x + threadIdx.x;   // exact: nbat*8*L*64
  int e = i & 63; int rest = i >> 6; int bh = rest / L;
  ctx[i] = mv[bh * 64 + e];
}

// full attention for the selected queries; scatter into ctx (chunk-local)
__global__ void k_sel_attn(const float* __restrict__ qkv, const int* __restrict__ top,
                           float* __restrict__ ctx, int L){
  __shared__ float qs[64];
  __shared__ float sc[336];
  int g = blockIdx.x; int e = threadIdx.x;
  int u = g % UTOP; int bh = g / UTOP; int b = bh >> 3, h = bh & 7;
  int t = top[bh * UTOP + u];
  qs[e] = qkv[(size_t)(b * L + t) * 1536 + h * 64 + e];
  __syncthreads();
  for (int s0 = e; s0 < L; s0 += 64){
    const float* Kr = qkv + (size_t)(b * L + s0) * 1536 + 512 + h * 64;
    float d = 0.f;
#pragma unroll
    for (int c = 0; c < 64; c++) d += qs[c] * Kr[c];
    sc[s0] = d * 0.125f;
  }
  __syncthreads();
  float m = -FLT_MAX;
  for (int s0 = e; s0 < L; s0 += 64) m = fmaxf(m, sc[s0]);
#pragma unroll
  for (int o = 32; o; o >>= 1) m = fmaxf(m, __shfl_xor(m, o));
  float zs = 0.f;
  for (int s0 = e; s0 < L; s0 += 64){ float ev = expf(sc[s0] - m); sc[s0] = ev; zs += ev; }
#pragma unroll
  for (int o = 32; o; o >>= 1) zs += __shfl_xor(zs, o);
  __syncthreads();
  float acc = 0.f;
  for (int s0 = 0; s0 < L; s0++)
    acc += sc[s0] * qkv[(size_t)(b * L + s0) * 1536 + 1024 + h * 64 + e];
  ctx[(size_t)(bh * L + t) * 64 + e] = acc / zs;
}

// ctx (nbat,H,L,64) -> flat (nbat*L,512). mix=0: [l][h*64+e]; mix=1: raw reshape.
__global__ void k_reshape(const float* __restrict__ ctx, float* __restrict__ out,
                          int L, int mix){
  int i = blockIdx.x * blockDim.x + threadIdx.x;   // exact: nbat*L*512
  int d = i & 511; int r = i >> 9; int b = r / L; int lp = r - b * L;
  int h, l, e;
  if (!mix){ h = d >> 6; e = d & 63; l = lp; }
  else {
    int flat = lp * 512 + d;         // = (h*L + l)*64 + e
    e = flat & 63; int hl = flat >> 6; l = hl % L; h = hl / L;
  }
  out[i] = ctx[((size_t)(b * 8 + h) * L + l) * 64 + e];
}

// LayerNorm over 512 (+optional residual), row-guarded, in-place safe.
__global__ void k_ln(const float* X, const float* Rs,
                     const float* __restrict__ g, const float* __restrict__ be,
                     float* Out, int rows){
  int row = (blockIdx.x << 2) + (threadIdx.x >> 6);
  if (row >= rows) return;                 // wave-uniform
  int lane = threadIdx.x & 63;
  const float* xr = X + (size_t)row * 512;
  const float* rr = Rs ? Rs + (size_t)row * 512 : nullptr;
  float v[8]; float sm = 0.f;
#pragma unroll
  for (int i = 0; i < 8; i++){
    int c = (i << 6) + lane;
    float t = xr[c] + (rr ? rr[c] : 0.f);
    v[i] = t; sm += t;
  }
#pragma unroll
  for (int o = 32; o; o >>= 1) sm += __shfl_xor(sm, o);
  float mean = sm * (1.f / 512.f);
  float ss = 0.f;
#pragma unroll
  for (int i = 0; i < 8; i++){ float dd = v[i] - mean; ss += dd * dd; }
#pragma unroll
  for (int o = 32; o; o >>= 1) ss += __shfl_xor(ss, o);
  float rst = rsqrtf(ss * (1.f / 512.f) + 1e-5f);
#pragma unroll
  for (int i = 0; i < 8; i++){
    int c = (i << 6) + lane;
    Out[(size_t)row * 512 + c] = (v[i] - mean) * rst * g[c] + be[c];
  }
}

// full cross attention: Q (rows,512) vs chunk KV (nbat,336,1024)=[K|V]
__global__ void k_cross_attn(const float* __restrict__ Q, const void* __restrict__ KV,
                             float* __restrict__ out, int L, int kvbf){
  __shared__ float qs[64];
  __shared__ float sc[336];
  int g = blockIdx.x; int e = threadIdx.x;
  int l = g % L; int bh = g / L; int b = bh >> 3, h = bh & 7;
  qs[e] = Q[(size_t)(b * L + l) * 512 + h * 64 + e];
  __syncthreads();
  for (int s0 = e; s0 < 336; s0 += 64){
    size_t base = (size_t)(b * 336 + s0) * 1024 + h * 64;
    float d = 0.f;
    if (kvbf){
      const u16* Kr = (const u16*)KV + base;
#pragma unroll
      for (int c = 0; c < 64; c++) d += qs[c] * bf2f(Kr[c]);
    } else {
      const float* Kr = (const float*)KV + base;
#pragma unroll
      for (int c = 0; c < 64; c++) d += qs[c] * Kr[c];
    }
    sc[s0] = d * 0.125f;
  }
  __syncthreads();
  float m = -FLT_MAX;
  for (int s0 = e; s0 < 336; s0 += 64) m = fmaxf(m, sc[s0]);
#pragma unroll
  for (int o = 32; o; o >>= 1) m = fmaxf(m, __shfl_xor(m, o));
  float zs = 0.f;
  for (int s0 = e; s0 < 336; s0 += 64){ float ev = expf(sc[s0] - m); sc[s0] = ev; zs += ev; }
#pragma unroll
  for (int o = 32; o; o >>= 1) zs += __shfl_xor(zs, o);
  __syncthreads();
  float acc = 0.f;
  for (int s0 = 0; s0 < 336; s0++){
    size_t base = (size_t)(b * 336 + s0) * 1024 + 512 + h * 64 + e;
    float vv = kvbf ? bf2f(((const u16*)KV)[base]) : ((const float*)KV)[base];
    acc += sc[s0] * vv;
  }
  out[(size_t)(b * L + l) * 512 + h * 64 + e] = acc / zs;
}

// final-LN of last position + scalar projection; out/hist pre-offset to chunk.
__global__ void k_final(const float* __restrict__ X, const float* __restrict__ g,
                        const float* __restrict__ be, const float* __restrict__ pw,
                        const float* __restrict__ pb, float* __restrict__ out,
                        float* __restrict__ hist, int L, int step){
  int b = blockIdx.x; int lane = threadIdx.x;
  const float* xr = X + (size_t)(b * L + (L - 1)) * 512;
  float v[8]; float sm = 0.f;
#pragma unroll
  for (int i = 0; i < 8; i++){ int c = (i << 6) + lane; v[i] = xr[c]; sm += v[i]; }
#pragma unroll
  for (int o = 32; o; o >>= 1) sm += __shfl_xor(sm, o);
  float mean = sm * (1.f / 512.f);
  float ss = 0.f;
#pragma unroll
  for (int i = 0; i < 8; i++){ float dd = v[i] - mean; ss += dd * dd; }
#pragma unroll
  for (int o = 32; o; o >>= 1) ss += __shfl_xor(ss, o);
  float rst = rsqrtf(ss * (1.f / 512.f) + 1e-5f);
  float acc = 0.f;
#pragma unroll
  for (int i = 0; i < 8; i++){
    int c = (i << 6) + lane;
    acc += ((v[i] - mean) * rst * g[c] + be[c]) * pw[c];
  }
#pragma unroll
  for (int o = 32; o; o >>= 1) acc += __shfl_xor(acc, o);
  if (lane == 0){
    float val = acc + pb[0];
    out[b * 12 + step] = val;
    hist[b * 180 + L] = val;
  }
}

__global__ void k_hist_init(const float* __restrict__ x, float* __restrict__ hist){
  int i = blockIdx.x * blockDim.x + threadIdx.x;   // exact 64*168
  int b = i / 168, l = i - b * 168;
  hist[b * 180 + l] = x[b * 336 + 168 + l];
}

// =====================================================================

extern "C" void kernel_launch(void* const* d_in, const int* in_sizes, int n_in,
                              void* d_out, int out_size, void* d_ws, size_t ws_size,
                              hipStream_t stream){
  (void)in_sizes; (void)n_in; (void)out_size;
  const float* input_x    = (const float*)d_in[0];
  const float* enc_emb_w  = (const float*)d_in[1];
  const float* dec_emb_w  = (const float*)d_in[2];
  const float* enc_attn_w = (const float*)d_in[3];
  const float* enc_attn_b = (const float*)d_in[4];
  const float* enc_ff1_w  = (const float*)d_in[5];
  const float* enc_ff1_b  = (const float*)d_in[6];
  const float* enc_ff2_w  = (const float*)d_in[7];
  const float* enc_ff2_b  = (const float*)d_in[8];
  const float* enc_ln_g   = (const float*)d_in[9];
  const float* enc_ln_b   = (const float*)d_in[10];
  const float* enc_fg     = (const float*)d_in[11];
  const float* enc_fb     = (const float*)d_in[12];
  const float* dec_self_w = (const float*)d_in[13];
  const float* dec_self_b = (const float*)d_in[14];
  const float* dec_cross_w= (const float*)d_in[15];
  const float* dec_cross_b= (const float*)d_in[16];
  const float* dec_ff1_w  = (const float*)d_in[17];
  const float* dec_ff1_b  = (const float*)d_in[18];
  const float* dec_ff2_w  = (const float*)d_in[19];
  const float* dec_ff2_b  = (const float*)d_in[20];
  const float* dec_ln_g   = (const float*)d_in[21];
  const float* dec_ln_b   = (const float*)d_in[22];
  const float* dec_fg     = (const float*)d_in[23];
  const float* dec_fb     = (const float*)d_in[24];
  const float* proj_w     = (const float*)d_in[25];
  const float* proj_b     = (const float*)d_in[26];
  float* out = (float*)d_out;

  // ---------- adaptive workspace plan (deterministic in ws_size) ----------
  char* p = (char*)d_ws;
  char* pend = p + ws_size;
  auto alloc = [&](size_t bytes)->char*{
    char* r = p; p += (bytes + 255) & ~(size_t)255; return r;
  };
  // Decide KV precision first: f32 KV needs 88MB fixed; require decent chunking.
  const size_t KV_ELEMS = (size_t)64 * 336 * 1024;
  const size_t SMALL = ((64*8*336 + 64*8*64 + 64*180) * 4 + (64*8*UTOP + 3*336*UTOP) * 4
                        + 8 * 256);
  size_t avail = ws_size > SMALL ? ws_size - SMALL : 0;
  const size_t ROWB = 3584 * 4;   // bytes/row of arena (A|Bq|ctx|D|C)
  int kvbf;
  {
    long cap32 = (long)((avail > KV_ELEMS * 4 ? avail - KV_ELEMS * 4 : 0) / ROWB);
    kvbf = (cap32 >= 4 * 336) ? 0 : 1;   // f32 KV only if >=4-batch enc chunks fit
  }
  void* KV = alloc(KV_ELEMS * (kvbf ? 2 : 4));
  float* M    = (float*)alloc((size_t)64*8*336*4);
  float* MV   = (float*)alloc((size_t)64*8*64*4);
  float* HIST = (float*)alloc((size_t)64*180*4);
  int* TOP  = (int*)alloc((size_t)64*8*UTOP*4);
  int* IDX0 = (int*)alloc((size_t)336*UTOP*4);
  int* IDX1 = (int*)alloc((size_t)336*UTOP*4);
  int* IDXD = (int*)alloc((size_t)336*UTOP*4);
  long cap_rows = (long)((size_t)(pend - p) / ROWB);
  int nb = 64; while (nb > 1 && (long)nb * 336 > cap_rows) nb >>= 1;
  int nd = 64; while (nd > 1 && (long)nd * 180 > cap_rows) nd >>= 1;
  long rowsMax = (long)nb * 336; if ((long)nd * 180 > rowsMax) rowsMax = (long)nd * 180;
  float* A   = (float*)p;
  float* Bq  = A   + rowsMax * 512;
  float* CTX = Bq  + rowsMax * 1536;
  float* D   = CTX + rowsMax * 512;
  float* C   = D   + rowsMax * 512;

  // ---------------- Encoder (chunked over batch) ----------------
  k_gen_idx<<<(336*UTOP + 255)/256, 256, 0, stream>>>(IDX0, 336, 336, 0u);
  k_gen_idx<<<(336*UTOP + 255)/256, 256, 0, stream>>>(IDX1, 336, 336, 1u);
  for (int c = 0; c < 64 / nb; c++){
    int b0 = c * nb; const int L = 336; int rows = nb * L;
    unsigned gy = (unsigned)((rows + 63) >> 6);
    k_embed<<<rows*2, 256, 0, stream>>>(input_x + (size_t)b0*336, enc_emb_w, A, L, 336);
    for (int l = 0; l < 2; l++){
      const float* aw = enc_attn_w + (size_t)l * 4 * 262144;
      const float* ab = enc_attn_b + (size_t)l * 2048;
      k_gemm512<<<dim3(24, gy), 256, 0, stream>>>(A, aw, ab, Bq, 1536, rows, 0);
      int nw = nb * 8 * L;
      k_prob_m<<<(nw + 3)/4, 256, 0, stream>>>(Bq, l ? IDX1 : IDX0, M, L, nw);
      k_topk<<<nb*8, 64, 0, stream>>>(M, TOP, L);
      k_meanv<<<nb*8, 64, 0, stream>>>(Bq, MV, L);
      k_ctx_init<<<rows*2, 256, 0, stream>>>(CTX, MV, L);
      k_sel_attn<<<nb*8*UTOP, 64, 0, stream>>>(Bq, TOP, CTX, L);
      k_reshape<<<rows*2, 256, 0, stream>>>(CTX, D, L, 0);
      k_gemm512<<<dim3(8, gy), 256, 0, stream>>>(D, aw + 3*262144, ab + 1536, C, 512, rows, 0);
      k_ln<<<(rows + 3)/4, 256, 0, stream>>>(A, C, enc_ln_g + l*1024, enc_ln_b + l*1024, A, rows);
      k_gemm512<<<dim3(8, gy), 256, 0, stream>>>(A, enc_ff1_w + (size_t)l*262144,
                                                 enc_ff1_b + l*512, D, 512, rows, 1);
      k_gemm512<<<dim3(8, gy), 256, 0, stream>>>(D, enc_ff2_w + (size_t)l*262144,
                                                 enc_ff2_b + l*512, C, 512, rows, 0);
      k_ln<<<(rows + 3)/4, 256, 0, stream>>>(A, C, enc_ln_g + l*1024 + 512,
                                             enc_ln_b + l*1024 + 512, A, rows);
    }
    k_ln<<<(rows + 3)/4, 256, 0, stream>>>(A, nullptr, enc_fg, enc_fb, CTX, rows);
    void* kvp = kvbf ? (void*)((u16*)KV + (size_t)b0*336*1024)
                     : (void*)((float*)KV + (size_t)b0*336*1024);
    k_gemm512<<<dim3(16, gy), 256, 0, stream>>>(CTX, dec_cross_w + 262144,
                                                dec_cross_b + 512, kvp, 1024, rows,
                                                kvbf ? 2 : 0);
  }
  k_hist_init<<<42, 256, 0, stream>>>(input_x, HIST);

  // ---------------- Decoder: 12 autoregressive steps (chunked) ----------------
  for (int t = 0; t < 12; t++){
    const int L = 168 + t;
    k_gen_idx<<<(L*UTOP + 255)/256, 256, 0, stream>>>(IDXD, L, L, (u32)(2 + t));
    for (int c = 0; c < 64 / nd; c++){
      int b0 = c * nd; int rows = nd * L;
      unsigned gy = (unsigned)((rows + 63) >> 6);
      k_embed<<<rows*2, 256, 0, stream>>>(HIST + (size_t)b0*180, dec_emb_w, A, L, 180);
      k_gemm512<<<dim3(24, gy), 256, 0, stream>>>(A, dec_self_w, dec_self_b, Bq, 1536, rows, 0);
      int nw = nd * 8 * L;
      k_prob_m<<<(nw + 3)/4, 256, 0, stream>>>(Bq, IDXD, M, L, nw);
      k_topk<<<nd*8, 64, 0, stream>>>(M, TOP, L);
      k_meanv<<<nd*8, 64, 0, stream>>>(Bq, MV, L);
      k_ctx_init<<<rows*2, 256, 0, stream>>>(CTX, MV, L);
      k_sel_attn<<<nd*8*UTOP, 64, 0, stream>>>(Bq, TOP, CTX, L);
      k_reshape<<<rows*2, 256, 0, stream>>>(CTX, D, L, 1);
      k_gemm512<<<dim3(8, gy), 256, 0, stream>>>(D, dec_self_w + 3*262144,
                                                 dec_self_b + 1536, C, 512, rows, 0);
      k_ln<<<(rows + 3)/4, 256, 0, stream>>>(A, C, dec_ln_g, dec_ln_b, A, rows);
      k_gemm512<<<dim3(8, gy), 256, 0, stream>>>(A, dec_cross_w, dec_cross_b, Bq, 512, rows, 0);
      void* kvp = kvbf ? (void*)((u16*)KV + (size_t)b0*336*1024)
                       : (void*)((float*)KV + (size_t)b0*336*1024);
      k_cross_attn<<<nd*8*L, 64, 0, stream>>>(Bq, kvp, D, L, kvbf);
      k_gemm512<<<dim3(8, gy), 256, 0, stream>>>(D, dec_cross_w + 3*262144,
                                                 dec_cross_b + 1536, C, 512, rows, 0);
      k_ln<<<(rows + 3)/4, 256, 0, stream>>>(A, C, dec_ln_g + 512, dec_ln_b + 512, A, rows);
      k_gemm512<<<dim3(8, gy), 256, 0, stream>>>(A, dec_ff1_w, dec_ff1_b, D, 512, rows, 1);
      k_gemm512<<<dim3(8, gy), 256, 0, stream>>>(D, dec_ff2_w, dec_ff2_b, C, 512, rows, 0);
      k_ln<<<(rows + 3)/4, 256, 0, stream>>>(A, C, dec_ln_g + 1024, dec_ln_b + 1024, A, rows);
      k_final<<<nd, 64, 0, stream>>>(A, dec_fg, dec_fb, proj_w, proj_b,
                                     out + (size_t)b0*12, HIST + (size_t)b0*180, L, t);
    }
  }
}

// Round 3
// 24384.402 us; speedup vs baseline: 1.4092x; 1.4092x over previous
//
#include <hip/hip_runtime.h>
#include <float.h>
#include <math.h>

// Informer forward, MI355X. GEMMs in bf16 MFMA (f32 accumulate); selection /
// softmax / LN math in f32. KV cross-cache bf16. Adaptive batch-chunking.
// B=64, STEPS=336, D_MODEL=512, H=8, DH=64, E_LAYERS=2, D_LAYERS=1, D_FF=512,
// FACTOR=5 -> U=30, LABEL_LEN=168, PRED_LEN=12.

#define UTOP 30
typedef unsigned int u32;
typedef unsigned short u16;
typedef __attribute__((ext_vector_type(8))) short bf16x8;
typedef __attribute__((ext_vector_type(4))) float f32x4;

// ---------------- Threefry-2x32 (JAX partitionable path) ----------------
__device__ __forceinline__ u32 rotl32(u32 x, int d){ return (x<<d)|(x>>(32-d)); }

__device__ __forceinline__ void threefry(u32 k0, u32 k1, u32& x0, u32& x1){
  u32 k2 = k0 ^ k1 ^ 0x1BD11BDAu;
  x0 += k0; x1 += k1;
#define TFR(r) { x0 += x1; x1 = rotl32(x1,(r)); x1 ^= x0; }
  TFR(13) TFR(15) TFR(26) TFR(6)
  x0 += k1; x1 += k2 + 1u;
  TFR(17) TFR(29) TFR(16) TFR(24)
  x0 += k2; x1 += k0 + 2u;
  TFR(13) TFR(15) TFR(26) TFR(6)
  x0 += k0; x1 += k1 + 3u;
  TFR(17) TFR(29) TFR(16) TFR(24)
  x0 += k1; x1 += k2 + 4u;
  TFR(13) TFR(15) TFR(26) TFR(6)
  x0 += k2; x1 += k0 + 5u;
#undef TFR
}

__device__ __forceinline__ u16 f2bf(float f){
  u32 u = __float_as_uint(f);
  return (u16)((u + 0x7FFFu + ((u >> 16) & 1u)) >> 16);
}
__device__ __forceinline__ float bf2f(u16 h){ return __uint_as_float(((u32)h) << 16); }

__global__ void k_gen_idx(int* __restrict__ idx, int L, int span_i, u32 ctr){
  int n = L * UTOP;
  int j = blockIdx.x * blockDim.x + threadIdx.x;
  if (j >= n) return;
  u32 a0 = 0u, a1 = ctr; threefry(0u, 7u, a0, a1);
  u32 k1a = 0u, k1b = 0u; threefry(a0, a1, k1a, k1b);
  u32 k2a = 0u, k2b = 1u; threefry(a0, a1, k2a, k2b);
  u32 h0 = 0u, h1 = (u32)j; threefry(k1a, k1b, h0, h1);
  u32 l0 = 0u, l1 = (u32)j; threefry(k2a, k2b, l0, l1);
  u32 span = (u32)span_i;
  u32 mult = 65536u % span; mult = (mult * mult) % span;
  u32 off  = (((h0 % span) * mult) + (l0 % span)) % span;
  idx[j] = (int)off;
}

// weight f32 -> bf16 (n multiple of 4)
__global__ void k_f2bf(const float* __restrict__ in, u16* __restrict__ out, int n){
  int i = (blockIdx.x * blockDim.x + threadIdx.x) * 4;
  if (i >= n) return;
  float4 v = *(const float4*)(in + i);
  ushort4 o; o.x = f2bf(v.x); o.y = f2bf(v.y); o.z = f2bf(v.z); o.w = f2bf(v.w);
  *(ushort4*)(out + i) = o;
}

// ---------------- Embedding: wrap-conv(3) + sinusoidal PE ----------------
__global__ void k_embed(const float* __restrict__ x, const float* __restrict__ w,
                        float* __restrict__ out, u16* __restrict__ outbf,
                        int L, int xs){
  int i = blockIdx.x * blockDim.x + threadIdx.x;
  int d = i & 511; int r = i >> 9; int b = r / L; int l = r - b * L;
  int lm = (l == 0) ? L - 1 : l - 1;
  int lp = (l == L - 1) ? 0 : l + 1;
  const float* xb = x + b * xs;
  float tok = w[d*3] * xb[lm] + w[d*3+1] * xb[l] + w[d*3+2] * xb[lp];
  int jj = d >> 1;
  float div = expf((float)(2 * jj) * -0.017988946039015984f);
  float arg = (float)l * div;
  float pe = (d & 1) ? cosf(arg) : sinf(arg);
  float v = tok + pe;
  out[i] = v; outbf[i] = f2bf(v);
}

// ---- bf16 MFMA GEMM: Out[rows,O] = X[rows,512] @ W[O,512]^T + bias ----
// X,W bf16 row-major (K=512). grid (O/128, ceil(rows/128)), block 256 (4 waves).
// Each wave computes a 64x64 quadrant via 4x4 frags of 16x16x32 MFMA.
// flags: bit0 = exact GELU, bit1 = bf16 out.
#define LDK 40
__global__ __launch_bounds__(256) void k_gemm_mfma(
    const u16* __restrict__ X, const u16* __restrict__ W,
    const float* __restrict__ bias, void* __restrict__ Out,
    int O, int rows, int flags){
  __shared__ u16 LA[128 * LDK];
  __shared__ u16 LB[128 * LDK];
  int tid = threadIdx.x;
  int wave = tid >> 6, lane = tid & 63;
  int wr = (wave >> 1) << 6, wc = (wave & 1) << 6;
  int r0 = blockIdx.y << 7, c0 = blockIdx.x << 7;
  int srow = tid >> 1;            // 0..127
  int scol = (tid & 1) << 4;      // 0 or 16
  int xr = r0 + srow; if (xr >= rows) xr = rows - 1;
  const u16* xp = X + (size_t)xr * 512 + scol;
  const u16* wp = W + (size_t)(c0 + srow) * 512 + scol;
  u16* la = &LA[srow * LDK + scol];
  u16* lb = &LB[srow * LDK + scol];
  int fr = lane & 15;
  int fk = (lane >> 4) << 3;      // 0,8,16,24
  f32x4 acc[4][4];
#pragma unroll
  for (int i = 0; i < 4; i++)
#pragma unroll
    for (int j = 0; j < 4; j++) acc[i][j] = (f32x4)0.f;
  for (int k0 = 0; k0 < 512; k0 += 32){
    *(uint4*)la       = *(const uint4*)(xp + k0);
    *(uint4*)(la + 8) = *(const uint4*)(xp + k0 + 8);
    *(uint4*)lb       = *(const uint4*)(wp + k0);
    *(uint4*)(lb + 8) = *(const uint4*)(wp + k0 + 8);
    __syncthreads();
    bf16x8 af[4], bg[4];
#pragma unroll
    for (int i = 0; i < 4; i++){
      af[i] = *(const bf16x8*)&LA[(wr + i*16 + fr) * LDK + fk];
      bg[i] = *(const bf16x8*)&LB[(wc + i*16 + fr) * LDK + fk];
    }
#pragma unroll
    for (int i = 0; i < 4; i++)
#pragma unroll
      for (int j = 0; j < 4; j++)
        acc[i][j] = __builtin_amdgcn_mfma_f32_16x16x32_bf16(af[i], bg[j], acc[i][j], 0, 0, 0);
    __syncthreads();
  }
  // C/D: col = lane&15, row = (lane>>4)*4 + q   [m89-verified]
  int rbase = r0 + wr + ((lane >> 4) << 2);
#pragma unroll
  for (int i = 0; i < 4; i++){
#pragma unroll
    for (int q = 0; q < 4; q++){
      int row = rbase + i*16 + q;
      if (row >= rows) continue;
#pragma unroll
      for (int j = 0; j < 4; j++){
        int col = c0 + wc + j*16 + fr;
        float t = acc[i][j][q] + bias[col];
        if (flags & 1) t = 0.5f * t * (1.0f + erff(t * 0.7071067811865476f));
        if (flags & 2) ((u16*)Out)[(size_t)row * O + col] = f2bf(t);
        else           ((float*)Out)[(size_t)row * O + col] = t;
      }
    }
  }
}

// ---------------- ProbAttention M-scores ----------------
__global__ void k_prob_m(const float* __restrict__ qkv, const int* __restrict__ idx,
                         float* __restrict__ M, int L, int nwaves){
  int w = (blockIdx.x << 2) + (threadIdx.x >> 6);
  if (w >= nwaves) return;
  int lane = threadIdx.x & 63;
  int l = w % L; int bh = w / L; int b = bh >> 3, h = bh & 7;
  float q = qkv[(size_t)(b * L + l) * 1536 + h * 64 + lane];
  float mx = -FLT_MAX, sm = 0.f;
  for (int u = 0; u < UTOP; u++){
    int ki = idx[l * UTOP + u];
    float kv = qkv[(size_t)(b * L + ki) * 1536 + 512 + h * 64 + lane];
    float p = q * kv;
#pragma unroll
    for (int o = 32; o; o >>= 1) p += __shfl_xor(p, o);
    mx = fmaxf(mx, p); sm += p;
  }
  if (lane == 0) M[w] = mx - sm / (float)L;
}

__global__ void k_topk(const float* __restrict__ M, int* __restrict__ top, int L){
  __shared__ float s[336];
  int bh = blockIdx.x; int lane = threadIdx.x;
  for (int l = lane; l < L; l += 64) s[l] = M[bh * L + l];
  __syncthreads();
  for (int u = 0; u < UTOP; u++){
    float bv = -FLT_MAX; int bi = 0x7FFFFFFF;
    for (int l = lane; l < L; l += 64){
      float v = s[l];
      if (v > bv || (v == bv && l < bi)){ bv = v; bi = l; }
    }
#pragma unroll
    for (int o = 32; o; o >>= 1){
      float ov = __shfl_xor(bv, o); int oi = __shfl_xor(bi, o);
      if (ov > bv || (ov == bv && oi < bi)){ bv = ov; bi = oi; }
    }
    if (lane == 0){ top[bh * UTOP + u] = bi; s[bi] = -FLT_MAX; }
    __syncthreads();
  }
}

__global__ void k_meanv(const float* __restrict__ qkv, float* __restrict__ mv, int L){
  int bh = blockIdx.x; int e = threadIdx.x;
  int b = bh >> 3, h = bh & 7;
  float sm = 0.f;
  for (int l = 0; l < L; l++)
    sm += qkv[(size_t)(b * L + l) * 1536 + 1024 + h * 64 + e];
  mv[bh * 64 + e] = sm / (float)L;
}

__global__ void k_ctx_init(float* __restrict__ ctx, const float* __restrict__ mv, int L){
  int i = blockIdx.x * blockDim.x + threadIdx.x;
  int e = i & 63; int rest = i >> 6; int bh = rest / L;
  ctx[i] = mv[bh * 64 + e];
}

__global__ void k_sel_attn(const float* __restrict__ qkv, const int* __restrict__ top,
                           float* __restrict__ ctx, int L){
  __shared__ float qs[64];
  __shared__ float sc[336];
  int g = blockIdx.x; int e = threadIdx.x;
  int u = g % UTOP; int bh = g / UTOP; int b = bh >> 3, h = bh & 7;
  int t = top[bh * UTOP + u];
  qs[e] = qkv[(size_t)(b * L + t) * 1536 + h * 64 + e];
  __syncthreads();
  for (int s0 = e; s0 < L; s0 += 64){
    const float* Kr = qkv + (size_t)(b * L + s0) * 1536 + 512 + h * 64;
    float d = 0.f;
#pragma unroll
    for (int c = 0; c < 64; c++) d += qs[c] * Kr[c];
    sc[s0] = d * 0.125f;
  }
  __syncthreads();
  float m = -FLT_MAX;
  for (int s0 = e; s0 < L; s0 += 64) m = fmaxf(m, sc[s0]);
#pragma unroll
  for (int o = 32; o; o >>= 1) m = fmaxf(m, __shfl_xor(m, o));
  float zs = 0.f;
  for (int s0 = e; s0 < L; s0 += 64){ float ev = expf(sc[s0] - m); sc[s0] = ev; zs += ev; }
#pragma unroll
  for (int o = 32; o; o >>= 1) zs += __shfl_xor(zs, o);
  __syncthreads();
  float acc = 0.f;
  for (int s0 = 0; s0 < L; s0++)
    acc += sc[s0] * qkv[(size_t)(b * L + s0) * 1536 + 1024 + h * 64 + e];
  ctx[(size_t)(bh * L + t) * 64 + e] = acc / zs;
}

// ctx (nbat,H,L,64) -> bf16 flat (nbat*L,512). mix=0: [l][h*64+e]; mix=1: raw.
__global__ void k_reshape(const float* __restrict__ ctx, u16* __restrict__ out,
                          int L, int mix){
  int i = blockIdx.x * blockDim.x + threadIdx.x;
  int d = i & 511; int r = i >> 9; int b = r / L; int lp = r - b * L;
  int h, l, e;
  if (!mix){ h = d >> 6; e = d & 63; l = lp; }
  else {
    int flat = lp * 512 + d;
    e = flat & 63; int hl = flat >> 6; l = hl % L; h = hl / L;
  }
  out[i] = f2bf(ctx[((size_t)(b * 8 + h) * L + l) * 64 + e]);
}

// LayerNorm (+optional residual); writes f32 Out and optional bf16 OutBf.
__global__ void k_ln(const float* X, const float* Rs,
                     const float* __restrict__ g, const float* __restrict__ be,
                     float* Out, u16* OutBf, int rows){
  int row = (blockIdx.x << 2) + (threadIdx.x >> 6);
  if (row >= rows) return;
  int lane = threadIdx.x & 63;
  const float* xr = X + (size_t)row * 512;
  const float* rr = Rs ? Rs + (size_t)row * 512 : nullptr;
  float v[8]; float sm = 0.f;
#pragma unroll
  for (int i = 0; i < 8; i++){
    int c = (i << 6) + lane;
    float t = xr[c] + (rr ? rr[c] : 0.f);
    v[i] = t; sm += t;
  }
#pragma unroll
  for (int o = 32; o; o >>= 1) sm += __shfl_xor(sm, o);
  float mean = sm * (1.f / 512.f);
  float ss = 0.f;
#pragma unroll
  for (int i = 0; i < 8; i++){ float dd = v[i] - mean; ss += dd * dd; }
#pragma unroll
  for (int o = 32; o; o >>= 1) ss += __shfl_xor(ss, o);
  float rst = rsqrtf(ss * (1.f / 512.f) + 1e-5f);
#pragma unroll
  for (int i = 0; i < 8; i++){
    int c = (i << 6) + lane;
    float t = (v[i] - mean) * rst * g[c] + be[c];
    Out[(size_t)row * 512 + c] = t;
    if (OutBf) OutBf[(size_t)row * 512 + c] = f2bf(t);
  }
}

// full cross attention: Q f32 (rows,512) vs chunk KV bf16 (nbat,336,1024)=[K|V]
// out bf16 (rows,512)
__global__ void k_cross_attn(const float* __restrict__ Q, const u16* __restrict__ KV,
                             u16* __restrict__ out, int L){
  __shared__ float qs[64];
  __shared__ float sc[336];
  int g = blockIdx.x; int e = threadIdx.x;
  int l = g % L; int bh = g / L; int b = bh >> 3, h = bh & 7;
  qs[e] = Q[(size_t)(b * L + l) * 512 + h * 64 + e];
  __syncthreads();
  for (int s0 = e; s0 < 336; s0 += 64){
    const u16* Kr = KV + (size_t)(b * 336 + s0) * 1024 + h * 64;
    float d = 0.f;
#pragma unroll
    for (int c = 0; c < 64; c++) d += qs[c] * bf2f(Kr[c]);
    sc[s0] = d * 0.125f;
  }
  __syncthreads();
  float m = -FLT_MAX;
  for (int s0 = e; s0 < 336; s0 += 64) m = fmaxf(m, sc[s0]);
#pragma unroll
  for (int o = 32; o; o >>= 1) m = fmaxf(m, __shfl_xor(m, o));
  float zs = 0.f;
  for (int s0 = e; s0 < 336; s0 += 64){ float ev = expf(sc[s0] - m); sc[s0] = ev; zs += ev; }
#pragma unroll
  for (int o = 32; o; o >>= 1) zs += __shfl_xor(zs, o);
  __syncthreads();
  float acc = 0.f;
  for (int s0 = 0; s0 < 336; s0++)
    acc += sc[s0] * bf2f(KV[(size_t)(b * 336 + s0) * 1024 + 512 + h * 64 + e]);
  out[(size_t)(b * L + l) * 512 + h * 64 + e] = f2bf(acc / zs);
}

__global__ void k_final(const float* __restrict__ X, const float* __restrict__ g,
                        const float* __restrict__ be, const float* __restrict__ pw,
                        const float* __restrict__ pb, float* __restrict__ out,
                        float* __restrict__ hist, int L, int step){
  int b = blockIdx.x; int lane = threadIdx.x;
  const float* xr = X + (size_t)(b * L + (L - 1)) * 512;
  float v[8]; float sm = 0.f;
#pragma unroll
  for (int i = 0; i < 8; i++){ int c = (i << 6) + lane; v[i] = xr[c]; sm += v[i]; }
#pragma unroll
  for (int o = 32; o; o >>= 1) sm += __shfl_xor(sm, o);
  float mean = sm * (1.f / 512.f);
  float ss = 0.f;
#pragma unroll
  for (int i = 0; i < 8; i++){ float dd = v[i] - mean; ss += dd * dd; }
#pragma unroll
  for (int o = 32; o; o >>= 1) ss += __shfl_xor(ss, o);
  float rst = rsqrtf(ss * (1.f / 512.f) + 1e-5f);
  float acc = 0.f;
#pragma unroll
  for (int i = 0; i < 8; i++){
    int c = (i << 6) + lane;
    acc += ((v[i] - mean) * rst * g[c] + be[c]) * pw[c];
  }
#pragma unroll
  for (int o = 32; o; o >>= 1) acc += __shfl_xor(acc, o);
  if (lane == 0){
    float val = acc + pb[0];
    out[b * 12 + step] = val;
    hist[b * 180 + L] = val;
  }
}

__global__ void k_hist_init(const float* __restrict__ x, float* __restrict__ hist){
  int i = blockIdx.x * blockDim.x + threadIdx.x;
  int b = i / 168, l = i - b * 168;
  hist[b * 180 + l] = x[b * 336 + 168 + l];
}

// =====================================================================

extern "C" void kernel_launch(void* const* d_in, const int* in_sizes, int n_in,
                              void* d_out, int out_size, void* d_ws, size_t ws_size,
                              hipStream_t stream){
  (void)in_sizes; (void)n_in; (void)out_size;
  const float* input_x    = (const float*)d_in[0];
  const float* enc_emb_w  = (const float*)d_in[1];
  const float* dec_emb_w  = (const float*)d_in[2];
  const float* enc_attn_w = (const float*)d_in[3];
  const float* enc_attn_b = (const float*)d_in[4];
  const float* enc_ff1_w  = (const float*)d_in[5];
  const float* enc_ff1_b  = (const float*)d_in[6];
  const float* enc_ff2_w  = (const float*)d_in[7];
  const float* enc_ff2_b  = (const float*)d_in[8];
  const float* enc_ln_g   = (const float*)d_in[9];
  const float* enc_ln_b   = (const float*)d_in[10];
  const float* enc_fg     = (const float*)d_in[11];
  const float* enc_fb     = (const float*)d_in[12];
  const float* dec_self_w = (const float*)d_in[13];
  const float* dec_self_b = (const float*)d_in[14];
  const float* dec_cross_w= (const float*)d_in[15];
  const float* dec_cross_b= (const float*)d_in[16];
  const float* dec_ff1_w  = (const float*)d_in[17];
  const float* dec_ff1_b  = (const float*)d_in[18];
  const float* dec_ff2_w  = (const float*)d_in[19];
  const float* dec_ff2_b  = (const float*)d_in[20];
  const float* dec_ln_g   = (const float*)d_in[21];
  const float* dec_ln_b   = (const float*)d_in[22];
  const float* dec_fg     = (const float*)d_in[23];
  const float* dec_fb     = (const float*)d_in[24];
  const float* proj_w     = (const float*)d_in[25];
  const float* proj_b     = (const float*)d_in[26];
  float* out = (float*)d_out;

  // ---------- adaptive workspace plan ----------
  char* p = (char*)d_ws;
  char* pend = p + ws_size;
  auto alloc = [&](size_t bytes)->char*{
    char* r = p; p += (bytes + 255) & ~(size_t)255; return r;
  };
  // bf16 weights
  u16* WBencA = (u16*)alloc((size_t)2*4*262144*2);
  u16* WBencF1= (u16*)alloc((size_t)2*262144*2);
  u16* WBencF2= (u16*)alloc((size_t)2*262144*2);
  u16* WBdecS = (u16*)alloc((size_t)4*262144*2);
  u16* WBdecC = (u16*)alloc((size_t)4*262144*2);
  u16* WBdecF1= (u16*)alloc((size_t)262144*2);
  u16* WBdecF2= (u16*)alloc((size_t)262144*2);
  u16* KV     = (u16*)alloc((size_t)64*336*1024*2);   // bf16 cross K|V
  float* M    = (float*)alloc((size_t)64*8*336*4);
  float* MV   = (float*)alloc((size_t)64*8*64*4);
  float* HIST = (float*)alloc((size_t)64*180*4);
  int* TOP  = (int*)alloc((size_t)64*8*UTOP*4);
  int* IDX0 = (int*)alloc((size_t)336*UTOP*4);
  int* IDX1 = (int*)alloc((size_t)336*UTOP*4);
  int* IDXD = (int*)alloc((size_t)336*UTOP*4);
  // per-row arena: A f32 + Abf bf16 + Bq f32 + C f32 (ctx alias) + Dbf bf16
  const size_t ROWB = 512*4 + 512*2 + 1536*4 + 512*4 + 512*2;   // 12288 B
  long cap_rows = (long)((size_t)(pend - p) / ROWB);
  int nb = 64; while (nb > 1 && (long)nb * 336 > cap_rows) nb >>= 1;
  int nd = 64; while (nd > 1 && (long)nd * 180 > cap_rows) nd >>= 1;
  long rowsMax = (long)nb * 336; if ((long)nd * 180 > rowsMax) rowsMax = (long)nd * 180;
  float* A   = (float*)p;
  u16*  Abf  = (u16*)(A + rowsMax * 512);
  float* Bq  = (float*)(Abf + rowsMax * 512);
  float* C   = Bq + rowsMax * 1536;          // also the ctx buffer
  u16*  Dbf  = (u16*)(C + rowsMax * 512);

  // ---------- weight conversion (every call; ws is re-poisoned) ----------
  {
    auto cvt = [&](const float* src, u16* dst, int n){
      k_f2bf<<<(n/4 + 255)/256, 256, 0, stream>>>(src, dst, n);
    };
    cvt(enc_attn_w, WBencA, 2*4*262144);
    cvt(enc_ff1_w,  WBencF1, 2*262144);
    cvt(enc_ff2_w,  WBencF2, 2*262144);
    cvt(dec_self_w, WBdecS, 4*262144);
    cvt(dec_cross_w,WBdecC, 4*262144);
    cvt(dec_ff1_w,  WBdecF1, 262144);
    cvt(dec_ff2_w,  WBdecF2, 262144);
  }

  // ---------------- Encoder (chunked over batch) ----------------
  k_gen_idx<<<(336*UTOP + 255)/256, 256, 0, stream>>>(IDX0, 336, 336, 0u);
  k_gen_idx<<<(336*UTOP + 255)/256, 256, 0, stream>>>(IDX1, 336, 336, 1u);
  for (int c = 0; c < 64 / nb; c++){
    int b0 = c * nb; const int L = 336; int rows = nb * L;
    unsigned gy = (unsigned)((rows + 127) >> 7);
    k_embed<<<rows*2, 256, 0, stream>>>(input_x + (size_t)b0*336, enc_emb_w, A, Abf, L, 336);
    for (int l = 0; l < 2; l++){
      const u16* aw = WBencA + (size_t)l * 4 * 262144;
      const float* ab = enc_attn_b + (size_t)l * 2048;
      k_gemm_mfma<<<dim3(12, gy), 256, 0, stream>>>(Abf, aw, ab, Bq, 1536, rows, 0);
      int nw = nb * 8 * L;
      k_prob_m<<<(nw + 3)/4, 256, 0, stream>>>(Bq, l ? IDX1 : IDX0, M, L, nw);
      k_topk<<<nb*8, 64, 0, stream>>>(M, TOP, L);
      k_meanv<<<nb*8, 64, 0, stream>>>(Bq, MV, L);
      k_ctx_init<<<rows*2, 256, 0, stream>>>(C, MV, L);
      k_sel_attn<<<nb*8*UTOP, 64, 0, stream>>>(Bq, TOP, C, L);
      k_reshape<<<rows*2, 256, 0, stream>>>(C, Dbf, L, 0);
      k_gemm_mfma<<<dim3(4, gy), 256, 0, stream>>>(Dbf, aw + 3*262144, ab + 1536, C, 512, rows, 0);
      k_ln<<<(rows + 3)/4, 256, 0, stream>>>(A, C, enc_ln_g + l*1024, enc_ln_b + l*1024, A, Abf, rows);
      k_gemm_mfma<<<dim3(4, gy), 256, 0, stream>>>(Abf, WBencF1 + (size_t)l*262144,
                                                   enc_ff1_b + l*512, Dbf, 512, rows, 3);
      k_gemm_mfma<<<dim3(4, gy), 256, 0, stream>>>(Dbf, WBencF2 + (size_t)l*262144,
                                                   enc_ff2_b + l*512, C, 512, rows, 0);
      k_ln<<<(rows + 3)/4, 256, 0, stream>>>(A, C, enc_ln_g + l*1024 + 512,
                                             enc_ln_b + l*1024 + 512, A, Abf, rows);
    }
    k_ln<<<(rows + 3)/4, 256, 0, stream>>>(A, nullptr, enc_fg, enc_fb, C, Abf, rows);
    k_gemm_mfma<<<dim3(8, gy), 256, 0, stream>>>(Abf, WBdecC + 262144, dec_cross_b + 512,
                                                 KV + (size_t)b0*336*1024, 1024, rows, 2);
  }
  k_hist_init<<<42, 256, 0, stream>>>(input_x, HIST);

  // ---------------- Decoder: 12 autoregressive steps (chunked) ----------------
  for (int t = 0; t < 12; t++){
    const int L = 168 + t;
    k_gen_idx<<<(L*UTOP + 255)/256, 256, 0, stream>>>(IDXD, L, L, (u32)(2 + t));
    for (int c = 0; c < 64 / nd; c++){
      int b0 = c * nd; int rows = nd * L;
      unsigned gy = (unsigned)((rows + 127) >> 7);
      k_embed<<<rows*2, 256, 0, stream>>>(HIST + (size_t)b0*180, dec_emb_w, A, Abf, L, 180);
      k_gemm_mfma<<<dim3(12, gy), 256, 0, stream>>>(Abf, WBdecS, dec_self_b, Bq, 1536, rows, 0);
      int nw = nd * 8 * L;
      k_prob_m<<<(nw + 3)/4, 256, 0, stream>>>(Bq, IDXD, M, L, nw);
      k_topk<<<nd*8, 64, 0, stream>>>(M, TOP, L);
      k_meanv<<<nd*8, 64, 0, stream>>>(Bq, MV, L);
      k_ctx_init<<<rows*2, 256, 0, stream>>>(C, MV, L);
      k_sel_attn<<<nd*8*UTOP, 64, 0, stream>>>(Bq, TOP, C, L);
      k_reshape<<<rows*2, 256, 0, stream>>>(C, Dbf, L, 1);
      k_gemm_mfma<<<dim3(4, gy), 256, 0, stream>>>(Dbf, WBdecS + 3*262144,
                                                   dec_self_b + 1536, C, 512, rows, 0);
      k_ln<<<(rows + 3)/4, 256, 0, stream>>>(A, C, dec_ln_g, dec_ln_b, A, Abf, rows);
      k_gemm_mfma<<<dim3(4, gy), 256, 0, stream>>>(Abf, WBdecC, dec_cross_b, Bq, 512, rows, 0);
      k_cross_attn<<<nd*8*L, 64, 0, stream>>>(Bq, KV + (size_t)b0*336*1024, Dbf, L);
      k_gemm_mfma<<<dim3(4, gy), 256, 0, stream>>>(Dbf, WBdecC + 3*262144,
                                                   dec_cross_b + 1536, C, 512, rows, 0);
      k_ln<<<(rows + 3)/4, 256, 0, stream>>>(A, C, dec_ln_g + 512, dec_ln_b + 512, A, Abf, rows);
      k_gemm_mfma<<<dim3(4, gy), 256, 0, stream>>>(Abf, WBdecF1, dec_ff1_b, Dbf, 512, rows, 3);
      k_gemm_mfma<<<dim3(4, gy), 256, 0, stream>>>(Dbf, WBdecF2, dec_ff2_b, C, 512, rows, 0);
      k_ln<<<(rows + 3)/4, 256, 0, stream>>>(A, C, dec_ln_g + 1024, dec_ln_b + 1024, A, nullptr, rows);
      k_final<<<nd, 64, 0, stream>>>(A, dec_fg, dec_fb, proj_w, proj_b,
                                     out + (size_t)b0*12, HIST + (size_t)b0*180, L, t);
    }
  }
}

// Round 6
// 6547.449 us; speedup vs baseline: 5.2482x; 3.7243x over previous
//
#include <hip/hip_runtime.h>
#include <float.h>
#include <math.h>

// Informer forward, MI355X. Round 4 kernel (2nd resubmit; GPU broker timeouts).
// - Decoder dead-code elimination: only head 7 / tail-8 rows matter per step.
// - Embed fused into GEMM A-staging (PE table); no decoder activation buffer.
// - Encoder: bf16 QKV + bf16 branch outputs (f32 residual trunk), SELPOS/UPD
//   gather instead of materialized ctx. Arena 8192 B/row -> bigger chunks.
// B=64, STEPS=336, D_MODEL=512, H=8, DH=64, E_LAYERS=2, D_LAYERS=1, D_FF=512,
// FACTOR=5 -> U=30, LABEL_LEN=168, PRED_LEN=12.

#define UTOP 30
typedef unsigned int u32;
typedef unsigned short u16;
typedef __attribute__((ext_vector_type(8))) short bf16x8;
typedef __attribute__((ext_vector_type(4))) float f32x4;

// ---------------- Threefry-2x32 (JAX partitionable path) ----------------
__device__ __forceinline__ u32 rotl32(u32 x, int d){ return (x<<d)|(x>>(32-d)); }

__device__ __forceinline__ void threefry(u32 k0, u32 k1, u32& x0, u32& x1){
  u32 k2 = k0 ^ k1 ^ 0x1BD11BDAu;
  x0 += k0; x1 += k1;
#define TFR(r) { x0 += x1; x1 = rotl32(x1,(r)); x1 ^= x0; }
  TFR(13) TFR(15) TFR(26) TFR(6)
  x0 += k1; x1 += k2 + 1u;
  TFR(17) TFR(29) TFR(16) TFR(24)
  x0 += k2; x1 += k0 + 2u;
  TFR(13) TFR(15) TFR(26) TFR(6)
  x0 += k0; x1 += k1 + 3u;
  TFR(17) TFR(29) TFR(16) TFR(24)
  x0 += k1; x1 += k2 + 4u;
  TFR(13) TFR(15) TFR(26) TFR(6)
  x0 += k2; x1 += k0 + 5u;
#undef TFR
}

__device__ __forceinline__ u16 f2bf(float f){
  u32 u = __float_as_uint(f);
  return (u16)((u + 0x7FFFu + ((u >> 16) & 1u)) >> 16);
}
__device__ __forceinline__ float bf2f(u16 h){ return __uint_as_float(((u32)h) << 16); }
__device__ __forceinline__ float gelu(float t){
  return 0.5f * t * (1.0f + erff(t * 0.7071067811865476f));
}

__global__ void k_gen_idx(int* __restrict__ idx, int L, int span_i, u32 ctr){
  int n = L * UTOP;
  int j = blockIdx.x * blockDim.x + threadIdx.x;
  if (j >= n) return;
  u32 a0 = 0u, a1 = ctr; threefry(0u, 7u, a0, a1);
  u32 k1a = 0u, k1b = 0u; threefry(a0, a1, k1a, k1b);
  u32 k2a = 0u, k2b = 1u; threefry(a0, a1, k2a, k2b);
  u32 h0 = 0u, h1 = (u32)j; threefry(k1a, k1b, h0, h1);
  u32 l0 = 0u, l1 = (u32)j; threefry(k2a, k2b, l0, l1);
  u32 span = (u32)span_i;
  u32 mult = 65536u % span; mult = (mult * mult) % span;
  u32 off  = (((h0 % span) * mult) + (l0 % span)) % span;
  idx[j] = (int)off;
}

__global__ void k_f2bf(const float* __restrict__ in, u16* __restrict__ out, int n){
  int i = (blockIdx.x * blockDim.x + threadIdx.x) * 4;
  if (i >= n) return;
  float4 v = *(const float4*)(in + i);
  ushort4 o; o.x = f2bf(v.x); o.y = f2bf(v.y); o.z = f2bf(v.z); o.w = f2bf(v.w);
  *(ushort4*)(out + i) = o;
}

// sinusoidal PE table, f32, 336x512
__global__ void k_pe(float* __restrict__ pe){
  int i = blockIdx.x * blockDim.x + threadIdx.x;   // exact 336*512
  int d = i & 511; int l = i >> 9;
  int jj = d >> 1;
  float div = expf((float)(2 * jj) * -0.017988946039015984f); // ln(10000)/512
  float arg = (float)l * div;
  pe[i] = (d & 1) ? cosf(arg) : sinf(arg);
}

// pack head-7 rows of dec_self_w Q,K,V into W192 bf16 (+bias)
__global__ void k_pack192(const float* __restrict__ w, const float* __restrict__ b,
                          u16* __restrict__ W192, float* __restrict__ B192){
  int i = blockIdx.x * blockDim.x + threadIdx.x;   // exact 192*512
  int r = i >> 9, c = i & 511;
  int srow = ((r >> 6) << 9) + 448 + (r & 63);
  W192[i] = f2bf(w[(size_t)srow * 512 + c]);
  if (i < 192) B192[i] = b[((i >> 6) << 9) + 448 + (i & 63)];
}

__global__ void k_hist_init(const float* __restrict__ x, float* __restrict__ hist){
  int i = blockIdx.x * blockDim.x + threadIdx.x;   // exact 64*168
  int b = i / 168, l = i - b * 168;
  hist[b * 180 + l] = x[b * 336 + 168 + l];
}

// ---- bf16 MFMA GEMM: Out[rows,O] = X[rows,512] @ W[O,512]^T + bias ----
// flags: bit0 GELU, bit1 bf16 out.
#define LDK 40
__global__ __launch_bounds__(256) void k_gemm_mfma(
    const u16* __restrict__ X, const u16* __restrict__ W,
    const float* __restrict__ bias, void* __restrict__ Out,
    int O, int rows, int flags){
  __shared__ u16 LA[128 * LDK];
  __shared__ u16 LB[128 * LDK];
  int tid = threadIdx.x;
  int wave = tid >> 6, lane = tid & 63;
  int wr = (wave >> 1) << 6, wc = (wave & 1) << 6;
  int r0 = blockIdx.y << 7, c0 = blockIdx.x << 7;
  int srow = tid >> 1;
  int scol = (tid & 1) << 4;
  int xr = r0 + srow; if (xr >= rows) xr = rows - 1;
  int wrow = c0 + srow; if (wrow >= O) wrow = O - 1;
  const u16* xp = X + (size_t)xr * 512 + scol;
  const u16* wp = W + (size_t)wrow * 512 + scol;
  u16* la = &LA[srow * LDK + scol];
  u16* lb = &LB[srow * LDK + scol];
  int fr = lane & 15;
  int fk = (lane >> 4) << 3;
  f32x4 acc[4][4];
#pragma unroll
  for (int i = 0; i < 4; i++)
#pragma unroll
    for (int j = 0; j < 4; j++) acc[i][j] = (f32x4)0.f;
  for (int k0 = 0; k0 < 512; k0 += 32){
    *(uint4*)la       = *(const uint4*)(xp + k0);
    *(uint4*)(la + 8) = *(const uint4*)(xp + k0 + 8);
    *(uint4*)lb       = *(const uint4*)(wp + k0);
    *(uint4*)(lb + 8) = *(const uint4*)(wp + k0 + 8);
    __syncthreads();
    bf16x8 af[4], bg[4];
#pragma unroll
    for (int i = 0; i < 4; i++){
      af[i] = *(const bf16x8*)&LA[(wr + i*16 + fr) * LDK + fk];
      bg[i] = *(const bf16x8*)&LB[(wc + i*16 + fr) * LDK + fk];
    }
#pragma unroll
    for (int i = 0; i < 4; i++)
#pragma unroll
      for (int j = 0; j < 4; j++)
        acc[i][j] = __builtin_amdgcn_mfma_f32_16x16x32_bf16(af[i], bg[j], acc[i][j], 0, 0, 0);
    __syncthreads();
  }
  int rbase = r0 + wr + ((lane >> 4) << 2);
#pragma unroll
  for (int i = 0; i < 4; i++){
#pragma unroll
    for (int q = 0; q < 4; q++){
      int row = rbase + i*16 + q;
      if (row >= rows) continue;
#pragma unroll
      for (int j = 0; j < 4; j++){
        int col = c0 + wc + j*16 + fr;
        if (col >= O) continue;
        float t = acc[i][j][q] + bias[col];
        if (flags & 1) t = gelu(t);
        if (flags & 2) ((u16*)Out)[(size_t)row * O + col] = f2bf(t);
        else           ((float*)Out)[(size_t)row * O + col] = t;
      }
    }
  }
}

// Same GEMM but A = embed(x) computed on the fly (wrap-conv3 + PE).
// x: per-batch series (stride xs), rows = nbat*L.
__global__ __launch_bounds__(256) void k_gemm_embed(
    const float* __restrict__ x, int xs, int L,
    const float* __restrict__ pe, const float* __restrict__ emb_w,
    const u16* __restrict__ W, const float* __restrict__ bias,
    void* __restrict__ Out, int O, int rows, int flags){
  __shared__ u16 LA[128 * LDK];
  __shared__ u16 LB[128 * LDK];
  __shared__ float EW[1536];
  int tid = threadIdx.x;
  for (int i = tid; i < 1536; i += 256) EW[i] = emb_w[i];
  int wave = tid >> 6, lane = tid & 63;
  int wr = (wave >> 1) << 6, wc = (wave & 1) << 6;
  int r0 = blockIdx.y << 7, c0 = blockIdx.x << 7;
  int srow = tid >> 1;
  int scol = (tid & 1) << 4;
  int xr = r0 + srow; if (xr >= rows) xr = rows - 1;
  int wrow = c0 + srow; if (wrow >= O) wrow = O - 1;
  int b = xr / L; int l = xr - b * L;
  int lm = (l == 0) ? L - 1 : l - 1;
  int lp = (l == L - 1) ? 0 : l + 1;
  const float* xb = x + b * xs;
  float x0 = xb[lm], x1 = xb[l], x2 = xb[lp];
  const float* per = pe + (size_t)l * 512 + scol;
  const u16* wp = W + (size_t)wrow * 512 + scol;
  u16* la = &LA[srow * LDK + scol];
  u16* lb = &LB[srow * LDK + scol];
  int fr = lane & 15;
  int fk = (lane >> 4) << 3;
  f32x4 acc[4][4];
#pragma unroll
  for (int i = 0; i < 4; i++)
#pragma unroll
    for (int j = 0; j < 4; j++) acc[i][j] = (f32x4)0.f;
  __syncthreads();   // EW ready
  for (int k0 = 0; k0 < 512; k0 += 32){
#pragma unroll
    for (int kk = 0; kk < 16; kk++){
      int k = k0 + scol + kk;
      float v = per[k0 + kk] + EW[k*3]*x0 + EW[k*3+1]*x1 + EW[k*3+2]*x2;
      la[kk] = f2bf(v);
    }
    *(uint4*)lb       = *(const uint4*)(wp + k0);
    *(uint4*)(lb + 8) = *(const uint4*)(wp + k0 + 8);
    __syncthreads();
    bf16x8 af[4], bg[4];
#pragma unroll
    for (int i = 0; i < 4; i++){
      af[i] = *(const bf16x8*)&LA[(wr + i*16 + fr) * LDK + fk];
      bg[i] = *(const bf16x8*)&LB[(wc + i*16 + fr) * LDK + fk];
    }
#pragma unroll
    for (int i = 0; i < 4; i++)
#pragma unroll
      for (int j = 0; j < 4; j++)
        acc[i][j] = __builtin_amdgcn_mfma_f32_16x16x32_bf16(af[i], bg[j], acc[i][j], 0, 0, 0);
    __syncthreads();
  }
  int rbase = r0 + wr + ((lane >> 4) << 2);
#pragma unroll
  for (int i = 0; i < 4; i++){
#pragma unroll
    for (int q = 0; q < 4; q++){
      int row = rbase + i*16 + q;
      if (row >= rows) continue;
#pragma unroll
      for (int j = 0; j < 4; j++){
        int col = c0 + wc + j*16 + fr;
        if (col >= O) continue;
        float t = acc[i][j][q] + bias[col];
        if (flags & 1) t = gelu(t);
        if (flags & 2) ((u16*)Out)[(size_t)row * O + col] = f2bf(t);
        else           ((float*)Out)[(size_t)row * O + col] = t;
      }
    }
  }
}

// ---------------- Encoder ProbAttention (QKV bf16, 1536 layout) -------------
__global__ void k_prob_m(const u16* __restrict__ qkv, const int* __restrict__ idx,
                         float* __restrict__ M, int L, int nwaves){
  int w = (blockIdx.x << 2) + (threadIdx.x >> 6);
  if (w >= nwaves) return;
  int lane = threadIdx.x & 63;
  int l = w % L; int bh = w / L; int b = bh >> 3, h = bh & 7;
  float q = bf2f(qkv[(size_t)(b * L + l) * 1536 + h * 64 + lane]);
  float mx = -FLT_MAX, sm = 0.f;
  for (int u = 0; u < UTOP; u++){
    int ki = idx[l * UTOP + u];
    float kv = bf2f(qkv[(size_t)(b * L + ki) * 1536 + 512 + h * 64 + lane]);
    float p = q * kv;
#pragma unroll
    for (int o = 32; o; o >>= 1) p += __shfl_xor(p, o);
    mx = fmaxf(mx, p); sm += p;
  }
  if (lane == 0) M[w] = mx - sm / (float)L;
}

// per-bh: meanV + clear SELPOS + stable top-30 (writes TOP + SELPOS)
__global__ void k_topk_mv(const float* __restrict__ M, const u16* __restrict__ qkv,
                          int* __restrict__ top, char* __restrict__ selpos,
                          float* __restrict__ mv, int L){
  __shared__ float s[336];
  int bh = blockIdx.x; int lane = threadIdx.x;
  int b = bh >> 3, h = bh & 7;
  float sm = 0.f;
  for (int l = 0; l < L; l++)
    sm += bf2f(qkv[(size_t)(b * L + l) * 1536 + 1024 + h * 64 + lane]);
  mv[bh * 64 + lane] = sm / (float)L;
  for (int l = lane; l < L; l += 64){ s[l] = M[bh * L + l]; selpos[bh * L + l] = 0; }
  __syncthreads();
  for (int u = 0; u < UTOP; u++){
    float bv = -FLT_MAX; int bi = 0x7FFFFFFF;
    for (int l = lane; l < L; l += 64){
      float v = s[l];
      if (v > bv || (v == bv && l < bi)){ bv = v; bi = l; }
    }
#pragma unroll
    for (int o = 32; o; o >>= 1){
      float ov = __shfl_xor(bv, o); int oi = __shfl_xor(bi, o);
      if (ov > bv || (ov == bv && oi < bi)){ bv = ov; bi = oi; }
    }
    if (lane == 0){ top[bh * UTOP + u] = bi; s[bi] = -FLT_MAX; selpos[bh * L + bi] = (char)(u + 1); }
    __syncthreads();
  }
}

// full attention for selected queries -> UPD[bh][u][e]
__global__ void k_sel_attn(const u16* __restrict__ qkv, const int* __restrict__ top,
                           float* __restrict__ upd, int L){
  __shared__ float qs[64];
  __shared__ float sc[336];
  int g = blockIdx.x; int e = threadIdx.x;
  int u = g % UTOP; int bh = g / UTOP; int b = bh >> 3, h = bh & 7;
  int t = top[bh * UTOP + u];
  qs[e] = bf2f(qkv[(size_t)(b * L + t) * 1536 + h * 64 + e]);
  __syncthreads();
  for (int s0 = e; s0 < L; s0 += 64){
    const u16* Kr = qkv + (size_t)(b * L + s0) * 1536 + 512 + h * 64;
    float d = 0.f;
#pragma unroll
    for (int c = 0; c < 64; c++) d += qs[c] * bf2f(Kr[c]);
    sc[s0] = d * 0.125f;
  }
  __syncthreads();
  float m = -FLT_MAX;
  for (int s0 = e; s0 < L; s0 += 64) m = fmaxf(m, sc[s0]);
#pragma unroll
  for (int o = 32; o; o >>= 1) m = fmaxf(m, __shfl_xor(m, o));
  float zs = 0.f;
  for (int s0 = e; s0 < L; s0 += 64){ float ev = expf(sc[s0] - m); sc[s0] = ev; zs += ev; }
#pragma unroll
  for (int o = 32; o; o >>= 1) zs += __shfl_xor(zs, o);
  __syncthreads();
  float acc = 0.f;
  for (int s0 = 0; s0 < L; s0++)
    acc += sc[s0] * bf2f(qkv[(size_t)(b * L + s0) * 1536 + 1024 + h * 64 + e]);
  upd[((size_t)bh * UTOP + u) * 64 + e] = acc / zs;
}

// gather ctx (meanV or UPD) -> bf16 flat (rows,512), mix=0 layout
__global__ void k_reshape_enc(const char* __restrict__ selpos,
                              const float* __restrict__ upd,
                              const float* __restrict__ mv,
                              u16* __restrict__ out, int L){
  int i = blockIdx.x * blockDim.x + threadIdx.x;   // exact rows*512
  int d = i & 511; int r = i >> 9; int b = r / L; int l = r - b * L;
  int h = d >> 6, e = d & 63;
  int bh = b * 8 + h;
  int p = selpos[bh * L + l];
  float v = p ? upd[((size_t)bh * UTOP + (p - 1)) * 64 + e] : mv[bh * 64 + e];
  out[i] = f2bf(v);
}

// LayerNorm: X f32 + optional bf16 residual branch; writes f32 (+opt bf16)
__global__ void k_ln(const float* __restrict__ X, const u16* __restrict__ Rs,
                     const float* __restrict__ g, const float* __restrict__ be,
                     float* __restrict__ Out, u16* __restrict__ OutBf, int rows){
  int row = (blockIdx.x << 2) + (threadIdx.x >> 6);
  if (row >= rows) return;
  int lane = threadIdx.x & 63;
  const float* xr = X + (size_t)row * 512;
  const u16* rr = Rs ? Rs + (size_t)row * 512 : nullptr;
  float v[8]; float sm = 0.f;
#pragma unroll
  for (int i = 0; i < 8; i++){
    int c = (i << 6) + lane;
    float t = xr[c] + (rr ? bf2f(rr[c]) : 0.f);
    v[i] = t; sm += t;
  }
#pragma unroll
  for (int o = 32; o; o >>= 1) sm += __shfl_xor(sm, o);
  float mean = sm * (1.f / 512.f);
  float ss = 0.f;
#pragma unroll
  for (int i = 0; i < 8; i++){ float dd = v[i] - mean; ss += dd * dd; }
#pragma unroll
  for (int o = 32; o; o >>= 1) ss += __shfl_xor(ss, o);
  float rst = rsqrtf(ss * (1.f / 512.f) + 1e-5f);
#pragma unroll
  for (int i = 0; i < 8; i++){
    int c = (i << 6) + lane;
    float t = (v[i] - mean) * rst * g[c] + be[c];
    Out[(size_t)row * 512 + c] = t;
    if (OutBf) OutBf[(size_t)row * 512 + c] = f2bf(t);
  }
}

// LayerNorm where X = embed(x) recomputed on the fly. lfix>=0: row==b, l=lfix.
__global__ void k_ln_embedres(const float* __restrict__ x, int xs, int L, int lfix,
                              const float* __restrict__ pe, const float* __restrict__ emb_w,
                              const u16* __restrict__ Rs,
                              const float* __restrict__ g, const float* __restrict__ be,
                              float* __restrict__ Out, u16* __restrict__ OutBf, int rows){
  int row = (blockIdx.x << 2) + (threadIdx.x >> 6);
  if (row >= rows) return;
  int lane = threadIdx.x & 63;
  int b, l;
  if (lfix >= 0){ b = row; l = lfix; } else { b = row / L; l = row - b * L; }
  int lm = (l == 0) ? L - 1 : l - 1;
  int lp = (l == L - 1) ? 0 : l + 1;
  const float* xb = x + b * xs;
  float x0 = xb[lm], x1 = xb[l], x2 = xb[lp];
  const float* per = pe + (size_t)l * 512;
  const u16* rr = Rs + (size_t)row * 512;
  float v[8]; float sm = 0.f;
#pragma unroll
  for (int i = 0; i < 8; i++){
    int c = (i << 6) + lane;
    float emb = per[c] + emb_w[c*3]*x0 + emb_w[c*3+1]*x1 + emb_w[c*3+2]*x2;
    float t = emb + bf2f(rr[c]);
    v[i] = t; sm += t;
  }
#pragma unroll
  for (int o = 32; o; o >>= 1) sm += __shfl_xor(sm, o);
  float mean = sm * (1.f / 512.f);
  float ss = 0.f;
#pragma unroll
  for (int i = 0; i < 8; i++){ float dd = v[i] - mean; ss += dd * dd; }
#pragma unroll
  for (int o = 32; o; o >>= 1) ss += __shfl_xor(ss, o);
  float rst = rsqrtf(ss * (1.f / 512.f) + 1e-5f);
#pragma unroll
  for (int i = 0; i < 8; i++){
    int c = (i << 6) + lane;
    float t = (v[i] - mean) * rst * g[c] + be[c];
    Out[(size_t)row * 512 + c] = t;
    if (OutBf) OutBf[(size_t)row * 512 + c] = f2bf(t);
  }
}

// ---------------- Decoder head-7 path (QKV192 bf16: [Q7|K7|V7]) -------------
__global__ void k_prob_m7(const u16* __restrict__ qkv, const int* __restrict__ idx,
                          float* __restrict__ M, int L, int nwaves){
  int w = (blockIdx.x << 2) + (threadIdx.x >> 6);
  if (w >= nwaves) return;
  int lane = threadIdx.x & 63;
  int l = w % L; int b = w / L;
  float q = bf2f(qkv[(size_t)(b * L + l) * 192 + lane]);
  float mx = -FLT_MAX, sm = 0.f;
  for (int u = 0; u < UTOP; u++){
    int ki = idx[l * UTOP + u];
    float kv = bf2f(qkv[(size_t)(b * L + ki) * 192 + 64 + lane]);
    float p = q * kv;
#pragma unroll
    for (int o = 32; o; o >>= 1) p += __shfl_xor(p, o);
    mx = fmaxf(mx, p); sm += p;
  }
  if (lane == 0) M[w] = mx - sm / (float)L;
}

// per-b: meanV -> all 8 tail slots of Dbf64; top-30 -> TOP7
__global__ void k_topk_mv7(const float* __restrict__ M, const u16* __restrict__ qkv,
                           int* __restrict__ top, u16* __restrict__ dbf, int L){
  __shared__ float s[336];
  int b = blockIdx.x; int lane = threadIdx.x;
  float sm = 0.f;
  for (int l = 0; l < L; l++)
    sm += bf2f(qkv[(size_t)(b * L + l) * 192 + 128 + lane]);
  u16 mvb = f2bf(sm / (float)L);
#pragma unroll
  for (int s8 = 0; s8 < 8; s8++) dbf[b * 512 + s8 * 64 + lane] = mvb;
  for (int l = lane; l < L; l += 64) s[l] = M[b * L + l];
  __syncthreads();
  for (int u = 0; u < UTOP; u++){
    float bv = -FLT_MAX; int bi = 0x7FFFFFFF;
    for (int l = lane; l < L; l += 64){
      float v = s[l];
      if (v > bv || (v == bv && l < bi)){ bv = v; bi = l; }
    }
#pragma unroll
    for (int o = 32; o; o >>= 1){
      float ov = __shfl_xor(bv, o); int oi = __shfl_xor(bi, o);
      if (ov > bv || (ov == bv && oi < bi)){ bv = ov; bi = oi; }
    }
    if (lane == 0){ top[b * UTOP + u] = bi; s[bi] = -FLT_MAX; }
    __syncthreads();
  }
}

// attention only for selected rows landing in tail-8 -> Dbf64 slot
__global__ void k_sel_attn7(const u16* __restrict__ qkv, const int* __restrict__ top,
                            u16* __restrict__ dbf, int L){
  __shared__ float qs[64];
  __shared__ float sc[336];
  int g = blockIdx.x; int e = threadIdx.x;
  int u = g % UTOP; int b = g / UTOP;
  int t = top[b * UTOP + u];
  if (t < L - 8) return;            // block-uniform early exit
  qs[e] = bf2f(qkv[(size_t)(b * L + t) * 192 + e]);
  __syncthreads();
  for (int s0 = e; s0 < L; s0 += 64){
    const u16* Kr = qkv + (size_t)(b * L + s0) * 192 + 64;
    float d = 0.f;
#pragma unroll
    for (int c = 0; c < 64; c++) d += qs[c] * bf2f(Kr[c]);
    sc[s0] = d * 0.125f;
  }
  __syncthreads();
  float m = -FLT_MAX;
  for (int s0 = e; s0 < L; s0 += 64) m = fmaxf(m, sc[s0]);
#pragma unroll
  for (int o = 32; o; o >>= 1) m = fmaxf(m, __shfl_xor(m, o));
  float zs = 0.f;
  for (int s0 = e; s0 < L; s0 += 64){ float ev = expf(sc[s0] - m); sc[s0] = ev; zs += ev; }
#pragma unroll
  for (int o = 32; o; o >>= 1) zs += __shfl_xor(zs, o);
  __syncthreads();
  float acc = 0.f;
  for (int s0 = 0; s0 < L; s0++)
    acc += sc[s0] * bf2f(qkv[(size_t)(b * L + s0) * 192 + 128 + e]);
  dbf[b * 512 + (t - (L - 8)) * 64 + e] = f2bf(acc / zs);
}

// cross attention for the single last row: Q64 f32 (64,512) vs KV bf16
__global__ void k_cross64(const float* __restrict__ Q, const u16* __restrict__ KV,
                          u16* __restrict__ out){
  __shared__ float qs[64];
  __shared__ float sc[336];
  int g = blockIdx.x; int e = threadIdx.x;
  int b = g >> 3, h = g & 7;
  qs[e] = Q[b * 512 + h * 64 + e];
  __syncthreads();
  for (int s0 = e; s0 < 336; s0 += 64){
    const u16* Kr = KV + (size_t)(b * 336 + s0) * 1024 + h * 64;
    float d = 0.f;
#pragma unroll
    for (int c = 0; c < 64; c++) d += qs[c] * bf2f(Kr[c]);
    sc[s0] = d * 0.125f;
  }
  __syncthreads();
  float m = -FLT_MAX;
  for (int s0 = e; s0 < 336; s0 += 64) m = fmaxf(m, sc[s0]);
#pragma unroll
  for (int o = 32; o; o >>= 1) m = fmaxf(m, __shfl_xor(m, o));
  float zs = 0.f;
  for (int s0 = e; s0 < 336; s0 += 64){ float ev = expf(sc[s0] - m); sc[s0] = ev; zs += ev; }
#pragma unroll
  for (int o = 32; o; o >>= 1) zs += __shfl_xor(zs, o);
  __syncthreads();
  float acc = 0.f;
  for (int s0 = 0; s0 < 336; s0++)
    acc += sc[s0] * bf2f(KV[(size_t)(b * 336 + s0) * 1024 + 512 + h * 64 + e]);
  out[b * 512 + h * 64 + e] = f2bf(acc / zs);
}

// final LN + scalar projection; X is (64,512) f32 row per batch
__global__ void k_final(const float* __restrict__ X, const float* __restrict__ g,
                        const float* __restrict__ be, const float* __restrict__ pw,
                        const float* __restrict__ pb, float* __restrict__ out,
                        float* __restrict__ hist, int L, int step){
  int b = blockIdx.x; int lane = threadIdx.x;
  const float* xr = X + (size_t)b * 512;
  float v[8]; float sm = 0.f;
#pragma unroll
  for (int i = 0; i < 8; i++){ int c = (i << 6) + lane; v[i] = xr[c]; sm += v[i]; }
#pragma unroll
  for (int o = 32; o; o >>= 1) sm += __shfl_xor(sm, o);
  float mean = sm * (1.f / 512.f);
  float ss = 0.f;
#pragma unroll
  for (int i = 0; i < 8; i++){ float dd = v[i] - mean; ss += dd * dd; }
#pragma unroll
  for (int o = 32; o; o >>= 1) ss += __shfl_xor(ss, o);
  float rst = rsqrtf(ss * (1.f / 512.f) + 1e-5f);
  float acc = 0.f;
#pragma unroll
  for (int i = 0; i < 8; i++){
    int c = (i << 6) + lane;
    acc += ((v[i] - mean) * rst * g[c] + be[c]) * pw[c];
  }
#pragma unroll
  for (int o = 32; o; o >>= 1) acc += __shfl_xor(acc, o);
  if (lane == 0){
    float val = acc + pb[0];
    out[b * 12 + step] = val;
    hist[b * 180 + L] = val;
  }
}

// =====================================================================

extern "C" void kernel_launch(void* const* d_in, const int* in_sizes, int n_in,
                              void* d_out, int out_size, void* d_ws, size_t ws_size,
                              hipStream_t stream){
  (void)in_sizes; (void)n_in; (void)out_size;
  const float* input_x    = (const float*)d_in[0];
  const float* enc_emb_w  = (const float*)d_in[1];
  const float* dec_emb_w  = (const float*)d_in[2];
  const float* enc_attn_w = (const float*)d_in[3];
  const float* enc_attn_b = (const float*)d_in[4];
  const float* enc_ff1_w  = (const float*)d_in[5];
  const float* enc_ff1_b  = (const float*)d_in[6];
  const float* enc_ff2_w  = (const float*)d_in[7];
  const float* enc_ff2_b  = (const float*)d_in[8];
  const float* enc_ln_g   = (const float*)d_in[9];
  const float* enc_ln_b   = (const float*)d_in[10];
  const float* enc_fg     = (const float*)d_in[11];
  const float* enc_fb     = (const float*)d_in[12];
  const float* dec_self_w = (const float*)d_in[13];
  const float* dec_self_b = (const float*)d_in[14];
  const float* dec_cross_w= (const float*)d_in[15];
  const float* dec_cross_b= (const float*)d_in[16];
  const float* dec_ff1_w  = (const float*)d_in[17];
  const float* dec_ff1_b  = (const float*)d_in[18];
  const float* dec_ff2_w  = (const float*)d_in[19];
  const float* dec_ff2_b  = (const float*)d_in[20];
  const float* dec_ln_g   = (const float*)d_in[21];
  const float* dec_ln_b   = (const float*)d_in[22];
  const float* dec_fg     = (const float*)d_in[23];
  const float* dec_fb     = (const float*)d_in[24];
  const float* proj_w     = (const float*)d_in[25];
  const float* proj_b     = (const float*)d_in[26];
  float* out = (float*)d_out;

  // ---------- workspace plan ----------
  char* p = (char*)d_ws;
  char* pend = p + ws_size;
  auto alloc = [&](size_t bytes)->char*{
    char* r = p; p += (bytes + 255) & ~(size_t)255; return r;
  };
  // fixed (live across both phases)
  u16* WBdecC  = (u16*)alloc((size_t)4*262144*2);
  u16* WdecSO  = (u16*)alloc((size_t)262144*2);
  u16* WBdecF1 = (u16*)alloc((size_t)262144*2);
  u16* WBdecF2 = (u16*)alloc((size_t)262144*2);
  u16* W192    = (u16*)alloc((size_t)192*512*2);
  float* B192  = (float*)alloc(192*4);
  u16* KV      = (u16*)alloc((size_t)64*336*1024*2);
  float* PE    = (float*)alloc((size_t)336*512*4);
  float* HIST  = (float*)alloc((size_t)64*180*4);
  int* IDX0 = (int*)alloc((size_t)336*UTOP*4);
  int* IDX1 = (int*)alloc((size_t)336*UTOP*4);
  int* IDXD = (int*)alloc((size_t)336*UTOP*4);
  float* M7  = (float*)alloc((size_t)64*180*4);
  int* TOP7  = (int*)alloc((size_t)64*UTOP*4);
  float* A64 = (float*)alloc((size_t)64*512*4);
  u16* A64bf = (u16*)alloc((size_t)64*512*2);
  float* Q64 = (float*)alloc((size_t)64*512*4);
  u16* C64bf = (u16*)alloc((size_t)64*512*2);
  u16* D64bf = (u16*)alloc((size_t)64*512*2);

  // X overlay region
  char* X = p;
  size_t xavail = (size_t)(pend - X);
  // decoder overlay: QKV192 bf16 for all 64 batches at max L=179
  u16* dQKV = (u16*)X;
  // encoder overlay
  char* q = X;
  auto qal = [&](size_t bytes)->char*{
    char* r = q; q += (bytes + 255) & ~(size_t)255; return r;
  };
  u16* WBencA  = (u16*)qal((size_t)2*4*262144*2);
  u16* WBencF1 = (u16*)qal((size_t)2*262144*2);
  u16* WBencF2 = (u16*)qal((size_t)2*262144*2);
  size_t encw_end = (size_t)(q - X);
  int nb = 64;
  while (nb > 1){
    size_t need = encw_end
      + (((size_t)nb*8*336*4 + 255) & ~255UL)    // M
      + (((size_t)nb*8*64*4  + 255) & ~255UL)    // MV
      + (((size_t)nb*8*UTOP*4+ 255) & ~255UL)    // TOP
      + (((size_t)nb*8*336   + 255) & ~255UL)    // SELPOS
      + (((size_t)nb*8*UTOP*64*4 + 255) & ~255UL)// UPD
      + (size_t)nb*336*8192;                     // arena
    if (need <= xavail) break;
    nb >>= 1;
  }
  float* M    = (float*)qal((size_t)nb*8*336*4);
  float* MV   = (float*)qal((size_t)nb*8*64*4);
  int*   TOP  = (int*)qal((size_t)nb*8*UTOP*4);
  char*  SELP = (char*)qal((size_t)nb*8*336);
  float* UPD  = (float*)qal((size_t)nb*8*UTOP*64*4);
  size_t rowsE = (size_t)nb*336;
  float* A    = (float*)q;
  u16* Abf    = (u16*)(A + rowsE*512);
  u16* QKVbf  = Abf + rowsE*512;
  u16* Cbf    = QKVbf + rowsE*1536;
  u16* Dbf    = Cbf + rowsE*512;

  // ---------- setup ----------
  auto cvt = [&](const float* src, u16* dst, int n){
    k_f2bf<<<(n/4 + 255)/256, 256, 0, stream>>>(src, dst, n);
  };
  cvt(enc_attn_w, WBencA, 2*4*262144);
  cvt(enc_ff1_w,  WBencF1, 2*262144);
  cvt(enc_ff2_w,  WBencF2, 2*262144);
  cvt(dec_cross_w, WBdecC, 4*262144);
  cvt(dec_self_w + 3*262144, WdecSO, 262144);
  cvt(dec_ff1_w,  WBdecF1, 262144);
  cvt(dec_ff2_w,  WBdecF2, 262144);
  k_pack192<<<(192*512)/256, 256, 0, stream>>>(dec_self_w, dec_self_b, W192, B192);
  k_pe<<<(336*512)/256, 256, 0, stream>>>(PE);
  k_hist_init<<<42, 256, 0, stream>>>(input_x, HIST);
  k_gen_idx<<<(336*UTOP + 255)/256, 256, 0, stream>>>(IDX0, 336, 336, 0u);
  k_gen_idx<<<(336*UTOP + 255)/256, 256, 0, stream>>>(IDX1, 336, 336, 1u);

  // ---------- encoder (chunked over batch) ----------
  for (int c = 0; c < 64 / nb; c++){
    int b0 = c * nb; const int L = 336; int rows = nb * L;
    unsigned gy = (unsigned)((rows + 127) >> 7);
    unsigned gln = (unsigned)((rows + 3) >> 2);
    for (int l = 0; l < 2; l++){
      const u16* aw = WBencA + (size_t)l * 4 * 262144;
      const float* ab = enc_attn_b + (size_t)l * 2048;
      if (l == 0)
        k_gemm_embed<<<dim3(12, gy), 256, 0, stream>>>(input_x + (size_t)b0*336, 336, 336,
                                                       PE, enc_emb_w, aw, ab, QKVbf, 1536, rows, 2);
      else
        k_gemm_mfma<<<dim3(12, gy), 256, 0, stream>>>(Abf, aw, ab, QKVbf, 1536, rows, 2);
      int nw = nb * 8 * L;
      k_prob_m<<<(nw + 3)/4, 256, 0, stream>>>(QKVbf, l ? IDX1 : IDX0, M, L, nw);
      k_topk_mv<<<nb*8, 64, 0, stream>>>(M, QKVbf, TOP, SELP, MV, L);
      k_sel_attn<<<nb*8*UTOP, 64, 0, stream>>>(QKVbf, TOP, UPD, L);
      k_reshape_enc<<<rows*2, 256, 0, stream>>>(SELP, UPD, MV, Dbf, L);
      k_gemm_mfma<<<dim3(4, gy), 256, 0, stream>>>(Dbf, aw + 3*262144, ab + 1536, Cbf, 512, rows, 2);
      if (l == 0)
        k_ln_embedres<<<gln, 256, 0, stream>>>(input_x + (size_t)b0*336, 336, 336, -1,
                                               PE, enc_emb_w, Cbf,
                                               enc_ln_g, enc_ln_b, A, Abf, rows);
      else
        k_ln<<<gln, 256, 0, stream>>>(A, Cbf, enc_ln_g + 1024, enc_ln_b + 1024, A, Abf, rows);
      k_gemm_mfma<<<dim3(4, gy), 256, 0, stream>>>(Abf, WBencF1 + (size_t)l*262144,
                                                   enc_ff1_b + l*512, Dbf, 512, rows, 3);
      k_gemm_mfma<<<dim3(4, gy), 256, 0, stream>>>(Dbf, WBencF2 + (size_t)l*262144,
                                                   enc_ff2_b + l*512, Cbf, 512, rows, 2);
      k_ln<<<gln, 256, 0, stream>>>(A, Cbf, enc_ln_g + l*1024 + 512,
                                    enc_ln_b + l*1024 + 512, A, Abf, rows);
    }
    k_ln<<<gln, 256, 0, stream>>>(A, nullptr, enc_fg, enc_fb, A, Abf, rows);
    k_gemm_mfma<<<dim3(8, gy), 256, 0, stream>>>(Abf, WBdecC + 262144, dec_cross_b + 512,
                                                 KV + (size_t)b0*336*1024, 1024, rows, 2);
  }

  // ---------- decoder: 12 autoregressive steps, no batch chunking ----------
  for (int t = 0; t < 12; t++){
    const int L = 168 + t;
    int rows = 64 * L;
    k_gen_idx<<<(L*UTOP + 255)/256, 256, 0, stream>>>(IDXD, L, L, (u32)(2 + t));
    k_gemm_embed<<<dim3(2, (unsigned)((rows + 127) >> 7)), 256, 0, stream>>>(
        HIST, 180, L, PE, dec_emb_w, W192, B192, dQKV, 192, rows, 2);
    k_prob_m7<<<(rows + 3)/4, 256, 0, stream>>>(dQKV, IDXD, M7, L, rows);
    k_topk_mv7<<<64, 64, 0, stream>>>(M7, dQKV, TOP7, D64bf, L);
    k_sel_attn7<<<64*UTOP, 64, 0, stream>>>(dQKV, TOP7, D64bf, L);
    k_gemm_mfma<<<dim3(4, 1), 256, 0, stream>>>(D64bf, WdecSO, dec_self_b + 1536, C64bf, 512, 64, 2);
    k_ln_embedres<<<16, 256, 0, stream>>>(HIST, 180, L, L - 1, PE, dec_emb_w, C64bf,
                                          dec_ln_g, dec_ln_b, A64, A64bf, 64);
    k_gemm_mfma<<<dim3(4, 1), 256, 0, stream>>>(A64bf, WBdecC, dec_cross_b, Q64, 512, 64, 0);
    k_cross64<<<512, 64, 0, stream>>>(Q64, KV, D64bf);
    k_gemm_mfma<<<dim3(4, 1), 256, 0, stream>>>(D64bf, WBdecC + 3*262144,
                                                dec_cross_b + 1536, C64bf, 512, 64, 2);
    k_ln<<<16, 256, 0, stream>>>(A64, C64bf, dec_ln_g + 512, dec_ln_b + 512, A64, A64bf, 64);
    k_gemm_mfma<<<dim3(4, 1), 256, 0, stream>>>(A64bf, WBdecF1, dec_ff1_b, D64bf, 512, 64, 3);
    k_gemm_mfma<<<dim3(4, 1), 256, 0, stream>>>(D64bf, WBdecF2, dec_ff2_b, C64bf, 512, 64, 2);
    k_ln<<<16, 256, 0, stream>>>(A64, C64bf, dec_ln_g + 1024, dec_ln_b + 1024, A64, nullptr, 64);
    k_final<<<64, 64, 0, stream>>>(A64, dec_fg, dec_fb, proj_w, proj_b, out, HIST, L, t);
  }
}